// Round 2
// baseline (1684.509 us; speedup 1.0000x reference)
//
#include <hip/hip_runtime.h>
#include <hip/hip_bf16.h>

#define N_NODES 100000
#define N_EDGES 3200000
#define N_GRAPHS 512
#define NBUK 391               // dst buckets of 256 nodes
#define CAP 10240              // fixed slot capacity per bucket (mean 8184, sigma~90)
#define FILL_CHUNK 16384
#define FILL_BLOCKS ((N_EDGES + FILL_CHUNK - 1) / FILL_CHUNK)   // 196

__device__ __forceinline__ float blo(unsigned v) { return __uint_as_float(v << 16); }
__device__ __forceinline__ float bhi(unsigned v) { return __uint_as_float(v & 0xffff0000u); }

// ---------- pass 1: bin edges into fixed bucket slots, rank-trick ----------
// packed[bucket*CAP + slot] = src | (local_dst << 17). Stays live for the
// whole pipeline now (the gathers consume it directly; no CSR anymore).
__global__ __launch_bounds__(1024) void k_binfill(const int* __restrict__ ei,
                                                  int* __restrict__ gcnt,
                                                  unsigned* __restrict__ packed) {
    __shared__ int h[NBUK];
    __shared__ int base[NBUK];
    __shared__ int sb[NBUK];       // block-local exclusive scan of h
    __shared__ int sc[512];
    __shared__ unsigned buf[FILL_CHUNK] __attribute__((aligned(16)));
    int t = threadIdx.x;
    for (int i = t; i < NBUK; i += 1024) h[i] = 0;
    __syncthreads();
    int s0 = blockIdx.x * FILL_CHUNK;
    int ng = min(FILL_CHUNK, N_EDGES - s0) >> 2;   // 4-entry groups
    const int4* src4 = (const int4*)(ei + s0);
    const int4* dst4 = (const int4*)(ei + N_EDGES + s0);
    int4 sv[4], dv[4];
    int  rk[4][4];
#pragma unroll
    for (int g = 0; g < 4; g++) {
        int gi = t + g * 1024;
        if (gi < ng) {
            sv[g] = src4[gi];
            dv[g] = dst4[gi];
            rk[g][0] = atomicAdd(&h[dv[g].x >> 8], 1);
            rk[g][1] = atomicAdd(&h[dv[g].y >> 8], 1);
            rk[g][2] = atomicAdd(&h[dv[g].z >> 8], 1);
            rk[g][3] = atomicAdd(&h[dv[g].w >> 8], 1);
        }
    }
    __syncthreads();
    for (int i = t; i < NBUK; i += 1024) {
        int c = h[i];
        base[i] = c ? atomicAdd(&gcnt[i], c) : 0;
    }
    if (t < 512) sc[t] = (t < NBUK) ? h[t] : 0;
    __syncthreads();
    for (int off = 1; off < 512; off <<= 1) {
        int x = (t >= off && t < 512) ? sc[t - off] : 0;
        __syncthreads();
        if (t < 512) sc[t] += x;
        __syncthreads();
    }
    for (int i = t; i < NBUK; i += 1024) sb[i] = sc[i] - h[i];
    __syncthreads();
#pragma unroll
    for (int g = 0; g < 4; g++) {
        int gi = t + g * 1024;
        if (gi < ng) {
            int s[4] = {sv[g].x, sv[g].y, sv[g].z, sv[g].w};
            int d[4] = {dv[g].x, dv[g].y, dv[g].z, dv[g].w};
#pragma unroll
            for (int k = 0; k < 4; k++) {
                int bk = d[k] >> 8;
                buf[sb[bk] + rk[g][k]] = (unsigned)s[k] | (((unsigned)d[k] & 255u) << 17);
            }
        }
    }
    __syncthreads();
    int w = t >> 6, lane = t & 63;
    for (int bk = w; bk < NBUK; bk += 16) {
        int c = h[bk];
        if (!c) continue;
        unsigned* gp = packed + (size_t)bk * CAP + base[bk];
        int lb = sb[bk];
        for (int j = lane; j < c; j += 64) gp[j] = buf[lb + j];
    }
}

// ---------- pass 2 (NEW, replaces k_csr): per-node degree only ----------
// Fire-and-forget LDS atomics (no return value -> no rank dependency chain,
// no scatter, no scan). Diagnostic: if this is ~90us the mystery cost is the
// scan+atomic phase; if ~10us it was the rank-return/scatter chain.
__global__ __launch_bounds__(1024) void k_deg(const unsigned* __restrict__ packed,
                                              const int* __restrict__ gcnt,
                                              const int* __restrict__ batch,
                                              float* __restrict__ dinv,
                                              int* __restrict__ cnt) {
    __shared__ int deg[256];
    int t = threadIdx.x, b = blockIdx.x;
    if (t < 256) deg[t] = 0;
    __syncthreads();
    int n = gcnt[b];
    const unsigned* pb = packed + (size_t)b * CAP;
    int n4 = n >> 2;
    const uint4* pb4 = (const uint4*)pb;
    for (int i = t; i < n4; i += 1024) {
        uint4 p = pb4[i];
        atomicAdd(&deg[p.x >> 17], 1);
        atomicAdd(&deg[p.y >> 17], 1);
        atomicAdd(&deg[p.z >> 17], 1);
        atomicAdd(&deg[p.w >> 17], 1);
    }
    for (int i = (n4 << 2) + t; i < n; i += 1024) atomicAdd(&deg[pb[i] >> 17], 1);
    __syncthreads();
    if (t < 256) {
        int node = b * 256 + t;
        if (node < N_NODES) {
            dinv[node] = rsqrtf((float)deg[t] + 1.0f);
            atomicAdd(&cnt[batch[node]], 1);
        }
    }
}

// ---------- H1s = bf16( (x @ W1) * dinv[row] )  ([100000,128] @ [128,32]) ----------
__global__ void k_gemm1(const float* __restrict__ x, const float* __restrict__ W1,
                        const float* __restrict__ dinv, __hip_bfloat16* __restrict__ H1s) {
    __shared__ float Ws[128 * 32];
    __shared__ float xs[32 * 128];
    int t = threadIdx.x;
    const float4* W4 = (const float4*)W1;
    float4* Ws4 = (float4*)Ws;
#pragma unroll
    for (int i = 0; i < 4; i++) Ws4[t + 256 * i] = W4[t + 256 * i];
    int row0 = blockIdx.x * 32;
    const float4* x4 = (const float4*)(x + (size_t)row0 * 128);
    float4* xs4 = (float4*)xs;
#pragma unroll
    for (int i = 0; i < 4; i++) xs4[t + 256 * i] = x4[t + 256 * i];
    __syncthreads();
    int col = t & 31;
    int rb = (t >> 5) * 4;
    float a0 = 0.f, a1 = 0.f, a2 = 0.f, a3 = 0.f;
#pragma unroll 8
    for (int k = 0; k < 128; k++) {
        float w = Ws[k * 32 + col];
        a0 += xs[(rb + 0) * 128 + k] * w;
        a1 += xs[(rb + 1) * 128 + k] * w;
        a2 += xs[(rb + 2) * 128 + k] * w;
        a3 += xs[(rb + 3) * 128 + k] * w;
    }
    int r = row0 + rb;
    __hip_bfloat16* o = H1s + (size_t)r * 32 + col;
    o[0]  = __float2bfloat16(a0 * dinv[r + 0]);
    o[32] = __float2bfloat16(a1 * dinv[r + 1]);
    o[64] = __float2bfloat16(a2 * dinv[r + 2]);
    o[96] = __float2bfloat16(a3 * dinv[r + 3]);
}

// ---------- H2s = bf16( (h1 @ W2) * dinv[row] )  ([100000,32] @ [32,32]) ----------
__global__ void k_gemm2(const float* __restrict__ h1, const float* __restrict__ W2,
                        const float* __restrict__ dinv, __hip_bfloat16* __restrict__ H2s) {
    __shared__ float Ws[32 * 32];
    __shared__ float xs[32 * 32];
    int t = threadIdx.x;
    ((float4*)Ws)[t] = ((const float4*)W2)[t];
    int row0 = blockIdx.x * 32;
    ((float4*)xs)[t] = ((const float4*)(h1 + (size_t)row0 * 32))[t];
    __syncthreads();
    int col = t & 31;
    int rb = (t >> 5) * 4;
    float a0 = 0.f, a1 = 0.f, a2 = 0.f, a3 = 0.f;
#pragma unroll
    for (int k = 0; k < 32; k++) {
        float w = Ws[k * 32 + col];
        a0 += xs[(rb + 0) * 32 + k] * w;
        a1 += xs[(rb + 1) * 32 + k] * w;
        a2 += xs[(rb + 2) * 32 + k] * w;
        a3 += xs[(rb + 3) * 32 + k] * w;
    }
    int r = row0 + rb;
    __hip_bfloat16* o = H2s + (size_t)r * 32 + col;
    o[0]  = __float2bfloat16(a0 * dinv[r + 0]);
    o[32] = __float2bfloat16(a1 * dinv[r + 1]);
    o[64] = __float2bfloat16(a2 * dinv[r + 2]);
    o[96] = __float2bfloat16(a3 * dinv[r + 3]);
}

// ---------- layer-1 aggregation: bucket-per-block, LDS accumulator ----------
// Streams the bucket's packed run directly (no CSR). Each quarter-wave owns an
// edge: 16 lanes fetch the 64B H row, then ds_add_f32 (fire-and-forget) into
// acc[local_dst][feat]. Epilogue: self-loop + dinv + bias + relu.
__global__ __launch_bounds__(1024) void k_gatherB1(const unsigned* __restrict__ packed,
                                                   const int* __restrict__ gcnt,
                                                   const __hip_bfloat16* __restrict__ Hs,
                                                   const float* __restrict__ dinv,
                                                   const float* __restrict__ bias,
                                                   float* __restrict__ hout) {
    __shared__ float acc[256 * 32];
    int t = threadIdx.x, b = blockIdx.x;
    for (int i = t; i < 8192; i += 1024) acc[i] = 0.f;
    __syncthreads();
    int n = gcnt[b];
    const unsigned* pb = packed + (size_t)b * CAP;
    const unsigned* H32 = (const unsigned*)Hs;   // row stride 16 uints
    int lane = t & 63;
    int f2 = lane & 15, q = lane >> 4;
    int slot = (t >> 6) * 4 + q;                 // 0..63
    int e = slot;
    for (; e + 192 < n; e += 256) {
        unsigned p0 = pb[e], p1 = pb[e + 64], p2 = pb[e + 128], p3 = pb[e + 192];
        unsigned v0 = H32[(size_t)(p0 & 0x1FFFFu) * 16 + f2];
        unsigned v1 = H32[(size_t)(p1 & 0x1FFFFu) * 16 + f2];
        unsigned v2 = H32[(size_t)(p2 & 0x1FFFFu) * 16 + f2];
        unsigned v3 = H32[(size_t)(p3 & 0x1FFFFu) * 16 + f2];
        int a0 = (int)(p0 >> 17) * 32 + f2 * 2;
        int a1 = (int)(p1 >> 17) * 32 + f2 * 2;
        int a2 = (int)(p2 >> 17) * 32 + f2 * 2;
        int a3 = (int)(p3 >> 17) * 32 + f2 * 2;
        atomicAdd(&acc[a0], blo(v0)); atomicAdd(&acc[a0 + 1], bhi(v0));
        atomicAdd(&acc[a1], blo(v1)); atomicAdd(&acc[a1 + 1], bhi(v1));
        atomicAdd(&acc[a2], blo(v2)); atomicAdd(&acc[a2 + 1], bhi(v2));
        atomicAdd(&acc[a3], blo(v3)); atomicAdd(&acc[a3 + 1], bhi(v3));
    }
    for (; e < n; e += 64) {
        unsigned p = pb[e];
        unsigned v = H32[(size_t)(p & 0x1FFFFu) * 16 + f2];
        int a = (int)(p >> 17) * 32 + f2 * 2;
        atomicAdd(&acc[a], blo(v)); atomicAdd(&acc[a + 1], bhi(v));
    }
    __syncthreads();
    int nl = t >> 2, f0 = (t & 3) * 8;
    int node = b * 256 + nl;
    if (node < N_NODES) {
        float di = dinv[node];
#pragma unroll
        for (int j = 0; j < 8; j += 2) {
            unsigned vw = H32[(size_t)node * 16 + ((f0 + j) >> 1)];
            float sx = fmaxf((acc[nl * 32 + f0 + j]     + blo(vw)) * di + bias[f0 + j],     0.f);
            float sy = fmaxf((acc[nl * 32 + f0 + j + 1] + bhi(vw)) * di + bias[f0 + j + 1], 0.f);
            *(float2*)(hout + (size_t)node * 32 + f0 + j) = make_float2(sx, sy);
        }
    }
}

// ---------- layer-2 aggregation fused with mean-pool numerator ----------
__global__ __launch_bounds__(1024) void k_gatherB2(const unsigned* __restrict__ packed,
                                                   const int* __restrict__ gcnt,
                                                   const __hip_bfloat16* __restrict__ Hs,
                                                   const float* __restrict__ dinv,
                                                   const float* __restrict__ bias,
                                                   const int* __restrict__ batch,
                                                   float* __restrict__ pool) {
    __shared__ float acc[256 * 32];
    int t = threadIdx.x, b = blockIdx.x;
    for (int i = t; i < 8192; i += 1024) acc[i] = 0.f;
    __syncthreads();
    int n = gcnt[b];
    const unsigned* pb = packed + (size_t)b * CAP;
    const unsigned* H32 = (const unsigned*)Hs;
    int lane = t & 63;
    int f2 = lane & 15, q = lane >> 4;
    int slot = (t >> 6) * 4 + q;
    int e = slot;
    for (; e + 192 < n; e += 256) {
        unsigned p0 = pb[e], p1 = pb[e + 64], p2 = pb[e + 128], p3 = pb[e + 192];
        unsigned v0 = H32[(size_t)(p0 & 0x1FFFFu) * 16 + f2];
        unsigned v1 = H32[(size_t)(p1 & 0x1FFFFu) * 16 + f2];
        unsigned v2 = H32[(size_t)(p2 & 0x1FFFFu) * 16 + f2];
        unsigned v3 = H32[(size_t)(p3 & 0x1FFFFu) * 16 + f2];
        int a0 = (int)(p0 >> 17) * 32 + f2 * 2;
        int a1 = (int)(p1 >> 17) * 32 + f2 * 2;
        int a2 = (int)(p2 >> 17) * 32 + f2 * 2;
        int a3 = (int)(p3 >> 17) * 32 + f2 * 2;
        atomicAdd(&acc[a0], blo(v0)); atomicAdd(&acc[a0 + 1], bhi(v0));
        atomicAdd(&acc[a1], blo(v1)); atomicAdd(&acc[a1 + 1], bhi(v1));
        atomicAdd(&acc[a2], blo(v2)); atomicAdd(&acc[a2 + 1], bhi(v2));
        atomicAdd(&acc[a3], blo(v3)); atomicAdd(&acc[a3 + 1], bhi(v3));
    }
    for (; e < n; e += 64) {
        unsigned p = pb[e];
        unsigned v = H32[(size_t)(p & 0x1FFFFu) * 16 + f2];
        int a = (int)(p >> 17) * 32 + f2 * 2;
        atomicAdd(&acc[a], blo(v)); atomicAdd(&acc[a + 1], bhi(v));
    }
    __syncthreads();
    int nl = t >> 2, f0 = (t & 3) * 8;
    int node = b * 256 + nl;
    if (node < N_NODES) {
        float di = dinv[node];
        int g = batch[node];
#pragma unroll
        for (int j = 0; j < 8; j += 2) {
            unsigned vw = H32[(size_t)node * 16 + ((f0 + j) >> 1)];
            float sx = fmaxf((acc[nl * 32 + f0 + j]     + blo(vw)) * di + bias[f0 + j],     0.f);
            float sy = fmaxf((acc[nl * 32 + f0 + j + 1] + bhi(vw)) * di + bias[f0 + j + 1], 0.f);
            atomicAdd(&pool[(size_t)g * 32 + f0 + j],     sx);
            atomicAdd(&pool[(size_t)g * 32 + f0 + j + 1], sy);
        }
    }
}

// ---------- head ----------
__global__ void k_final(const float* __restrict__ pool, const int* __restrict__ cnt,
                        const float* __restrict__ Wl, const float* __restrict__ bl,
                        float* __restrict__ out) {
    int g = blockIdx.x * 256 + threadIdx.x;
    if (g >= N_GRAPHS) return;
    float inv = 1.0f / fmaxf((float)cnt[g], 1.0f);
    float a0 = bl[0], a1 = bl[1];
#pragma unroll
    for (int f = 0; f < 32; f++) {
        float p = pool[g * 32 + f] * inv;
        a0 += p * Wl[f * 2 + 0];
        a1 += p * Wl[f * 2 + 1];
    }
    out[g * 2 + 0] = a0;
    out[g * 2 + 1] = a1;
}

extern "C" void kernel_launch(void* const* d_in, const int* in_sizes, int n_in,
                              void* d_out, int out_size, void* d_ws, size_t ws_size,
                              hipStream_t stream) {
    const float* x    = (const float*)d_in[0];
    const int*   ei   = (const int*)d_in[1];
    const int*   batch= (const int*)d_in[2];
    const float* W1   = (const float*)d_in[3];
    const float* b1   = (const float*)d_in[4];
    const float* W2   = (const float*)d_in[5];
    const float* b2   = (const float*)d_in[6];
    const float* Wl   = (const float*)d_in[7];
    const float* bl   = (const float*)d_in[8];
    float* out = (float*)d_out;

    char* w = (char*)d_ws;
    size_t off = 0;
    auto take = [&](size_t bytes) -> char* {
        char* p = w + off;
        off = (off + bytes + 255) & ~(size_t)255;
        return p;
    };
    __hip_bfloat16* H1s = (__hip_bfloat16*)take((size_t)N_NODES * 32 * 2);
    float*          h1  = (float*)take((size_t)N_NODES * 32 * 4);
    // packed lives through the whole pipeline now (gathers consume it).
    unsigned*       packed = (unsigned*)take((size_t)NBUK * CAP * 4);
    __hip_bfloat16* H2s    = (__hip_bfloat16*)take((size_t)N_NODES * 32 * 2);
    float*    dinv   = (float*)take((size_t)N_NODES * 4);
    int*      gcnt   = (int*)  take((size_t)NBUK * 4);
    float*    pool   = (float*)take((size_t)N_GRAPHS * 32 * 4);
    int*      cnt    = (int*)  take((size_t)N_GRAPHS * 4);

    hipMemsetAsync(gcnt, 0, (size_t)NBUK * 4, stream);
    hipMemsetAsync(pool, 0, (size_t)N_GRAPHS * 32 * 4, stream);
    hipMemsetAsync(cnt, 0, (size_t)N_GRAPHS * 4, stream);

    k_binfill <<<FILL_BLOCKS, 1024, 0, stream>>>(ei, gcnt, packed);
    k_deg     <<<NBUK, 1024, 0, stream>>>(packed, gcnt, batch, dinv, cnt);
    k_gemm1   <<<N_NODES / 32, 256, 0, stream>>>(x, W1, dinv, H1s);
    k_gatherB1<<<NBUK, 1024, 0, stream>>>(packed, gcnt, H1s, dinv, b1, h1);
    k_gemm2   <<<N_NODES / 32, 256, 0, stream>>>(h1, W2, dinv, H2s);
    k_gatherB2<<<NBUK, 1024, 0, stream>>>(packed, gcnt, H2s, dinv, b2, batch, pool);
    k_final   <<<2, 256, 0, stream>>>(pool, cnt, Wl, bl, out);
}

// Round 3
// 684.169 us; speedup vs baseline: 2.4621x; 2.4621x over previous
//
#include <hip/hip_runtime.h>
#include <hip/hip_bf16.h>

#define N_NODES 100000
#define N_EDGES 3200000
#define N_GRAPHS 512
#define CAPN 80                 // per-node CSR slot capacity (mean deg 32, max ~65)

__device__ __forceinline__ float blo(unsigned v) { return __uint_as_float(v << 16); }
__device__ __forceinline__ float bhi(unsigned v) { return __uint_as_float(v & 0xffff0000u); }

// ---------- binning: one pass, direct to per-node slots ----------
// rank via global atomic-return on deg[dst] (100K counters, ~zero same-address
// collision within a wave), then scattered dword store. 12.5K blocks -> TLP
// hides the atomic+store latency (unlike the old 391-block k_csr).
__global__ __launch_bounds__(256) void k_bin(const int* __restrict__ ei,
                                             int* __restrict__ deg,
                                             int* __restrict__ csr) {
    int gi = blockIdx.x * 256 + threadIdx.x;
    if (gi >= N_EDGES / 4) return;
    int4 s = ((const int4*)ei)[gi];
    int4 d = ((const int4*)(ei + N_EDGES))[gi];
    int r0 = atomicAdd(&deg[d.x], 1);
    int r1 = atomicAdd(&deg[d.y], 1);
    int r2 = atomicAdd(&deg[d.z], 1);
    int r3 = atomicAdd(&deg[d.w], 1);
    if (r0 < CAPN) csr[d.x * CAPN + r0] = s.x;
    if (r1 < CAPN) csr[d.y * CAPN + r1] = s.y;
    if (r2 < CAPN) csr[d.z * CAPN + r2] = s.z;
    if (r3 < CAPN) csr[d.w * CAPN + r3] = s.w;
}

// ---------- per-node epilogue of binning: dinv + per-graph node counts ----------
__global__ __launch_bounds__(256) void k_fixup(const int* __restrict__ deg,
                                               const int* __restrict__ batch,
                                               float* __restrict__ dinv,
                                               int* __restrict__ cnt) {
    int n = blockIdx.x * 256 + threadIdx.x;
    if (n >= N_NODES) return;
    dinv[n] = rsqrtf((float)deg[n] + 1.0f);
    atomicAdd(&cnt[batch[n]], 1);
}

// ---------- H1s = bf16( (x @ W1) * dinv[row] )  ([100000,128] @ [128,32]) ----------
__global__ void k_gemm1(const float* __restrict__ x, const float* __restrict__ W1,
                        const float* __restrict__ dinv, __hip_bfloat16* __restrict__ H1s) {
    __shared__ float Ws[128 * 32];
    __shared__ float xs[32 * 128];
    int t = threadIdx.x;
    const float4* W4 = (const float4*)W1;
    float4* Ws4 = (float4*)Ws;
#pragma unroll
    for (int i = 0; i < 4; i++) Ws4[t + 256 * i] = W4[t + 256 * i];
    int row0 = blockIdx.x * 32;
    const float4* x4 = (const float4*)(x + (size_t)row0 * 128);
    float4* xs4 = (float4*)xs;
#pragma unroll
    for (int i = 0; i < 4; i++) xs4[t + 256 * i] = x4[t + 256 * i];
    __syncthreads();
    int col = t & 31;
    int rb = (t >> 5) * 4;
    float a0 = 0.f, a1 = 0.f, a2 = 0.f, a3 = 0.f;
#pragma unroll 8
    for (int k = 0; k < 128; k++) {
        float w = Ws[k * 32 + col];
        a0 += xs[(rb + 0) * 128 + k] * w;
        a1 += xs[(rb + 1) * 128 + k] * w;
        a2 += xs[(rb + 2) * 128 + k] * w;
        a3 += xs[(rb + 3) * 128 + k] * w;
    }
    int r = row0 + rb;
    __hip_bfloat16* o = H1s + (size_t)r * 32 + col;
    o[0]  = __float2bfloat16(a0 * dinv[r + 0]);
    o[32] = __float2bfloat16(a1 * dinv[r + 1]);
    o[64] = __float2bfloat16(a2 * dinv[r + 2]);
    o[96] = __float2bfloat16(a3 * dinv[r + 3]);
}

// ---------- H2s = bf16( (h1 @ W2) * dinv[row] )  ([100000,32] @ [32,32]) ----------
__global__ void k_gemm2(const float* __restrict__ h1, const float* __restrict__ W2,
                        const float* __restrict__ dinv, __hip_bfloat16* __restrict__ H2s) {
    __shared__ float Ws[32 * 32];
    __shared__ float xs[32 * 32];
    int t = threadIdx.x;
    ((float4*)Ws)[t] = ((const float4*)W2)[t];
    int row0 = blockIdx.x * 32;
    ((float4*)xs)[t] = ((const float4*)(h1 + (size_t)row0 * 32))[t];
    __syncthreads();
    int col = t & 31;
    int rb = (t >> 5) * 4;
    float a0 = 0.f, a1 = 0.f, a2 = 0.f, a3 = 0.f;
#pragma unroll
    for (int k = 0; k < 32; k++) {
        float w = Ws[k * 32 + col];
        a0 += xs[(rb + 0) * 32 + k] * w;
        a1 += xs[(rb + 1) * 32 + k] * w;
        a2 += xs[(rb + 2) * 32 + k] * w;
        a3 += xs[(rb + 3) * 32 + k] * w;
    }
    int r = row0 + rb;
    __hip_bfloat16* o = H2s + (size_t)r * 32 + col;
    o[0]  = __float2bfloat16(a0 * dinv[r + 0]);
    o[32] = __float2bfloat16(a1 * dinv[r + 1]);
    o[64] = __float2bfloat16(a2 * dinv[r + 2]);
    o[96] = __float2bfloat16(a3 * dinv[r + 3]);
}

// ---------- layer-1 aggregation: one wave per dst node, 32 edges in flight ----
__global__ void k_gather1(const __hip_bfloat16* __restrict__ Hs, const float* __restrict__ dinv,
                          const int* __restrict__ deg, const int* __restrict__ csr,
                          const float* __restrict__ bias, float* __restrict__ hout) {
    int wid = (blockIdx.x * 256 + threadIdx.x) >> 6;
    if (wid >= N_NODES) return;
    const unsigned* H32 = (const unsigned*)Hs;   // row stride 16 uints
    int lane = threadIdx.x & 63;
    int f2 = lane & 15;
    int q = lane >> 4;
    int beg = wid * CAPN;
    int end = beg + deg[wid];
    float ax = 0.f, ay = 0.f;
    int e = beg + q;
    for (; e + 28 < end; e += 32) {          // 8 edges in flight per quarter-wave
        int s0 = csr[e],      s1 = csr[e + 4],  s2 = csr[e + 8],  s3 = csr[e + 12];
        int s4 = csr[e + 16], s5 = csr[e + 20], s6 = csr[e + 24], s7 = csr[e + 28];
        unsigned v0 = H32[(size_t)s0 * 16 + f2];
        unsigned v1 = H32[(size_t)s1 * 16 + f2];
        unsigned v2 = H32[(size_t)s2 * 16 + f2];
        unsigned v3 = H32[(size_t)s3 * 16 + f2];
        unsigned v4 = H32[(size_t)s4 * 16 + f2];
        unsigned v5 = H32[(size_t)s5 * 16 + f2];
        unsigned v6 = H32[(size_t)s6 * 16 + f2];
        unsigned v7 = H32[(size_t)s7 * 16 + f2];
        ax += blo(v0) + blo(v1) + blo(v2) + blo(v3) + blo(v4) + blo(v5) + blo(v6) + blo(v7);
        ay += bhi(v0) + bhi(v1) + bhi(v2) + bhi(v3) + bhi(v4) + bhi(v5) + bhi(v6) + bhi(v7);
    }
    for (; e + 12 < end; e += 16) {
        int s0 = csr[e], s1 = csr[e + 4], s2 = csr[e + 8], s3 = csr[e + 12];
        unsigned v0 = H32[(size_t)s0 * 16 + f2];
        unsigned v1 = H32[(size_t)s1 * 16 + f2];
        unsigned v2 = H32[(size_t)s2 * 16 + f2];
        unsigned v3 = H32[(size_t)s3 * 16 + f2];
        ax += blo(v0) + blo(v1) + blo(v2) + blo(v3);
        ay += bhi(v0) + bhi(v1) + bhi(v2) + bhi(v3);
    }
    for (; e < end; e += 4) {
        unsigned v = H32[(size_t)csr[e] * 16 + f2];
        ax += blo(v); ay += bhi(v);
    }
    ax += __shfl_xor(ax, 16); ay += __shfl_xor(ay, 16);
    ax += __shfl_xor(ax, 32); ay += __shfl_xor(ay, 32);
    if (q == 0) {
        float di = dinv[wid];
        unsigned vw = H32[(size_t)wid * 16 + f2];
        float2 bb = *(const float2*)(bias + f2 * 2);
        float2 o;
        o.x = fmaxf((ax + blo(vw)) * di + bb.x, 0.f);
        o.y = fmaxf((ay + bhi(vw)) * di + bb.y, 0.f);
        *(float2*)(hout + (size_t)wid * 32 + f2 * 2) = o;
    }
}

// ---------- layer-2 aggregation fused with mean-pool numerator ----------
__global__ void k_gather2(const __hip_bfloat16* __restrict__ Hs, const float* __restrict__ dinv,
                          const int* __restrict__ deg, const int* __restrict__ csr,
                          const float* __restrict__ bias, const int* __restrict__ batch,
                          float* __restrict__ pool) {
    int wid = (blockIdx.x * 256 + threadIdx.x) >> 6;
    if (wid >= N_NODES) return;
    const unsigned* H32 = (const unsigned*)Hs;
    int lane = threadIdx.x & 63;
    int f2 = lane & 15;
    int q = lane >> 4;
    int beg = wid * CAPN;
    int end = beg + deg[wid];
    float ax = 0.f, ay = 0.f;
    int e = beg + q;
    for (; e + 28 < end; e += 32) {
        int s0 = csr[e],      s1 = csr[e + 4],  s2 = csr[e + 8],  s3 = csr[e + 12];
        int s4 = csr[e + 16], s5 = csr[e + 20], s6 = csr[e + 24], s7 = csr[e + 28];
        unsigned v0 = H32[(size_t)s0 * 16 + f2];
        unsigned v1 = H32[(size_t)s1 * 16 + f2];
        unsigned v2 = H32[(size_t)s2 * 16 + f2];
        unsigned v3 = H32[(size_t)s3 * 16 + f2];
        unsigned v4 = H32[(size_t)s4 * 16 + f2];
        unsigned v5 = H32[(size_t)s5 * 16 + f2];
        unsigned v6 = H32[(size_t)s6 * 16 + f2];
        unsigned v7 = H32[(size_t)s7 * 16 + f2];
        ax += blo(v0) + blo(v1) + blo(v2) + blo(v3) + blo(v4) + blo(v5) + blo(v6) + blo(v7);
        ay += bhi(v0) + bhi(v1) + bhi(v2) + bhi(v3) + bhi(v4) + bhi(v5) + bhi(v6) + bhi(v7);
    }
    for (; e + 12 < end; e += 16) {
        int s0 = csr[e], s1 = csr[e + 4], s2 = csr[e + 8], s3 = csr[e + 12];
        unsigned v0 = H32[(size_t)s0 * 16 + f2];
        unsigned v1 = H32[(size_t)s1 * 16 + f2];
        unsigned v2 = H32[(size_t)s2 * 16 + f2];
        unsigned v3 = H32[(size_t)s3 * 16 + f2];
        ax += blo(v0) + blo(v1) + blo(v2) + blo(v3);
        ay += bhi(v0) + bhi(v1) + bhi(v2) + bhi(v3);
    }
    for (; e < end; e += 4) {
        unsigned v = H32[(size_t)csr[e] * 16 + f2];
        ax += blo(v); ay += bhi(v);
    }
    ax += __shfl_xor(ax, 16); ay += __shfl_xor(ay, 16);
    ax += __shfl_xor(ax, 32); ay += __shfl_xor(ay, 32);
    if (q == 0) {
        float di = dinv[wid];
        unsigned vw = H32[(size_t)wid * 16 + f2];
        float2 bb = *(const float2*)(bias + f2 * 2);
        float vx = fmaxf((ax + blo(vw)) * di + bb.x, 0.f);
        float vy = fmaxf((ay + bhi(vw)) * di + bb.y, 0.f);
        int g = batch[wid];
        atomicAdd(&pool[(size_t)g * 32 + f2 * 2 + 0], vx);
        atomicAdd(&pool[(size_t)g * 32 + f2 * 2 + 1], vy);
    }
}

// ---------- head ----------
__global__ void k_final(const float* __restrict__ pool, const int* __restrict__ cnt,
                        const float* __restrict__ Wl, const float* __restrict__ bl,
                        float* __restrict__ out) {
    int g = blockIdx.x * 256 + threadIdx.x;
    if (g >= N_GRAPHS) return;
    float inv = 1.0f / fmaxf((float)cnt[g], 1.0f);
    float a0 = bl[0], a1 = bl[1];
#pragma unroll
    for (int f = 0; f < 32; f++) {
        float p = pool[g * 32 + f] * inv;
        a0 += p * Wl[f * 2 + 0];
        a1 += p * Wl[f * 2 + 1];
    }
    out[g * 2 + 0] = a0;
    out[g * 2 + 1] = a1;
}

extern "C" void kernel_launch(void* const* d_in, const int* in_sizes, int n_in,
                              void* d_out, int out_size, void* d_ws, size_t ws_size,
                              hipStream_t stream) {
    const float* x    = (const float*)d_in[0];
    const int*   ei   = (const int*)d_in[1];
    const int*   batch= (const int*)d_in[2];
    const float* W1   = (const float*)d_in[3];
    const float* b1   = (const float*)d_in[4];
    const float* W2   = (const float*)d_in[5];
    const float* b2   = (const float*)d_in[6];
    const float* Wl   = (const float*)d_in[7];
    const float* bl   = (const float*)d_in[8];
    float* out = (float*)d_out;

    char* w = (char*)d_ws;
    size_t off = 0;
    auto take = [&](size_t bytes) -> char* {
        char* p = w + off;
        off = (off + bytes + 255) & ~(size_t)255;
        return p;
    };
    __hip_bfloat16* H1s = (__hip_bfloat16*)take((size_t)N_NODES * 32 * 2);   //  6.4 MB
    float*          h1  = (float*)take((size_t)N_NODES * 32 * 4);            // 12.8 MB
    int*            csr = (int*)  take((size_t)N_NODES * CAPN * 4);          // 32.0 MB
    __hip_bfloat16* H2s = (__hip_bfloat16*)take((size_t)N_NODES * 32 * 2);   //  6.4 MB
    int*      deg    = (int*)  take((size_t)N_NODES * 4);
    float*    dinv   = (float*)take((size_t)N_NODES * 4);
    float*    pool   = (float*)take((size_t)N_GRAPHS * 32 * 4);
    int*      cnt    = (int*)  take((size_t)N_GRAPHS * 4);

    hipMemsetAsync(deg, 0, (size_t)N_NODES * 4, stream);
    hipMemsetAsync(pool, 0, (size_t)N_GRAPHS * 32 * 4, stream);
    hipMemsetAsync(cnt, 0, (size_t)N_GRAPHS * 4, stream);

    k_bin    <<<(N_EDGES / 4 + 255) / 256, 256, 0, stream>>>(ei, deg, csr);
    k_fixup  <<<(N_NODES + 255) / 256, 256, 0, stream>>>(deg, batch, dinv, cnt);
    k_gemm1  <<<N_NODES / 32, 256, 0, stream>>>(x, W1, dinv, H1s);
    k_gather1<<<N_NODES / 4, 256, 0, stream>>>(H1s, dinv, deg, csr, b1, h1);
    k_gemm2  <<<N_NODES / 32, 256, 0, stream>>>(h1, W2, dinv, H2s);
    k_gather2<<<N_NODES / 4, 256, 0, stream>>>(H2s, dinv, deg, csr, b2, batch, pool);
    k_final  <<<2, 256, 0, stream>>>(pool, cnt, Wl, bl, out);
}

// Round 4
// 520.942 us; speedup vs baseline: 3.2336x; 1.3133x over previous
//
#include <hip/hip_runtime.h>
#include <hip/hip_bf16.h>

#define N_NODES 100000
#define N_EDGES 3200000
#define N_GRAPHS 512
#define NBUK 391               // dst buckets of 256 nodes
#define CAP 10240              // fixed slot capacity per bucket (mean 8184, sigma~90)
#define FILL_CHUNK 16384
#define FILL_BLOCKS ((N_EDGES + FILL_CHUNK - 1) / FILL_CHUNK)   // 196

__device__ __forceinline__ float blo(unsigned v) { return __uint_as_float(v << 16); }
__device__ __forceinline__ float bhi(unsigned v) { return __uint_as_float(v & 0xffff0000u); }

// ---------- pass 1: bin edges into fixed bucket slots (round-1 proven) ----------
__global__ __launch_bounds__(1024) void k_binfill(const int* __restrict__ ei,
                                                  int* __restrict__ gcnt,
                                                  unsigned* __restrict__ packed) {
    __shared__ int h[NBUK];
    __shared__ int base[NBUK];
    __shared__ int sb[NBUK];       // block-local exclusive scan of h
    __shared__ int sc[512];
    __shared__ unsigned buf[FILL_CHUNK] __attribute__((aligned(16)));
    int t = threadIdx.x;
    for (int i = t; i < NBUK; i += 1024) h[i] = 0;
    __syncthreads();
    int s0 = blockIdx.x * FILL_CHUNK;
    int ng = min(FILL_CHUNK, N_EDGES - s0) >> 2;   // 4-entry groups
    const int4* src4 = (const int4*)(ei + s0);
    const int4* dst4 = (const int4*)(ei + N_EDGES + s0);
    int4 sv[4], dv[4];
    int  rk[4][4];
#pragma unroll
    for (int g = 0; g < 4; g++) {
        int gi = t + g * 1024;
        if (gi < ng) {
            sv[g] = src4[gi];
            dv[g] = dst4[gi];
            rk[g][0] = atomicAdd(&h[dv[g].x >> 8], 1);
            rk[g][1] = atomicAdd(&h[dv[g].y >> 8], 1);
            rk[g][2] = atomicAdd(&h[dv[g].z >> 8], 1);
            rk[g][3] = atomicAdd(&h[dv[g].w >> 8], 1);
        }
    }
    __syncthreads();
    for (int i = t; i < NBUK; i += 1024) {
        int c = h[i];
        base[i] = c ? atomicAdd(&gcnt[i], c) : 0;
    }
    if (t < 512) sc[t] = (t < NBUK) ? h[t] : 0;
    __syncthreads();
    for (int off = 1; off < 512; off <<= 1) {
        int x = (t >= off && t < 512) ? sc[t - off] : 0;
        __syncthreads();
        if (t < 512) sc[t] += x;
        __syncthreads();
    }
    for (int i = t; i < NBUK; i += 1024) sb[i] = sc[i] - h[i];
    __syncthreads();
#pragma unroll
    for (int g = 0; g < 4; g++) {
        int gi = t + g * 1024;
        if (gi < ng) {
            int s[4] = {sv[g].x, sv[g].y, sv[g].z, sv[g].w};
            int d[4] = {dv[g].x, dv[g].y, dv[g].z, dv[g].w};
#pragma unroll
            for (int k = 0; k < 4; k++) {
                int bk = d[k] >> 8;
                buf[sb[bk] + rk[g][k]] = (unsigned)s[k] | (((unsigned)d[k] & 255u) << 17);
            }
        }
    }
    __syncthreads();
    int w = t >> 6, lane = t & 63;
    for (int bk = w; bk < NBUK; bk += 16) {
        int c = h[bk];
        if (!c) continue;
        unsigned* gp = packed + (size_t)bk * CAP + base[bk];
        int lb = sb[bk];
        for (int j = lane; j < c; j += 64) gp[j] = buf[lb + j];
    }
}

// ---------- pass 2: per-bucket deg/rp/rpe/dinv/cnt + slotted CSR (round-1 proven) ----
__global__ __launch_bounds__(1024) void k_csr(const unsigned* __restrict__ packed,
                                              const int* __restrict__ gcnt,
                                              const int* __restrict__ batch,
                                              int* __restrict__ rp, int* __restrict__ rpe,
                                              float* __restrict__ dinv,
                                              int* __restrict__ csr, int* __restrict__ cnt) {
    __shared__ int deg[256];
    __shared__ int sd[256];
    __shared__ int nb0[256];
    __shared__ int lcsr[CAP] __attribute__((aligned(16)));
    int t = threadIdx.x;
    int b = blockIdx.x;
    if (t < 256) deg[t] = 0;
    __syncthreads();
    int n = gcnt[b];
    const unsigned* pb = packed + (size_t)b * CAP;
    unsigned pv[3][4];
    int rk[3][4];
#pragma unroll
    for (int g = 0; g < 3; g++) {
        int i0 = 4 * (t + g * 1024);
        if (i0 < n) {
            if (i0 + 3 < n) {
                uint4 p = *(const uint4*)(pb + i0);
                pv[g][0] = p.x; pv[g][1] = p.y; pv[g][2] = p.z; pv[g][3] = p.w;
            } else {
#pragma unroll
                for (int k = 0; k < 4; k++) pv[g][k] = (i0 + k < n) ? pb[i0 + k] : 0u;
            }
#pragma unroll
            for (int k = 0; k < 4; k++)
                if (i0 + k < n) rk[g][k] = atomicAdd(&deg[pv[g][k] >> 17], 1);
        }
    }
    __syncthreads();
    int d = (t < 256) ? deg[t] : 0;
    if (t < 256) sd[t] = d;
    __syncthreads();
    for (int off = 1; off < 256; off <<= 1) {
        int x = (t >= off && t < 256) ? sd[t - off] : 0;
        __syncthreads();
        if (t < 256) sd[t] += x;
        __syncthreads();
    }
    if (t < 256) {
        int l0 = sd[t] - d;           // local base within bucket
        nb0[t] = l0;
        int node = b * 256 + t;
        if (node < N_NODES) {
            rp[node] = b * CAP + l0;
            rpe[node] = b * CAP + l0 + d;
            dinv[node] = rsqrtf((float)d + 1.0f);
            atomicAdd(&cnt[batch[node]], 1);
        }
    }
    __syncthreads();
#pragma unroll
    for (int g = 0; g < 3; g++) {
        int i0 = 4 * (t + g * 1024);
        if (i0 < n) {
#pragma unroll
            for (int k = 0; k < 4; k++) {
                if (i0 + k < n) {
                    unsigned p = pv[g][k];
                    lcsr[nb0[p >> 17] + rk[g][k]] = (int)(p & 0x1FFFFu);
                }
            }
        }
    }
    __syncthreads();
    int n4 = (n + 3) >> 2;
    int4* dst4 = (int4*)(csr + (size_t)b * CAP);
    const int4* sl4 = (const int4*)lcsr;
    for (int i = t; i < n4; i += 1024) dst4[i] = sl4[i];
}

// ---------- H1s = bf16( (x @ W1) * dinv[row] )  ([100000,128] @ [128,32]) ----------
__global__ void k_gemm1(const float* __restrict__ x, const float* __restrict__ W1,
                        const float* __restrict__ dinv, __hip_bfloat16* __restrict__ H1s) {
    __shared__ float Ws[128 * 32];
    __shared__ float xs[32 * 128];
    int t = threadIdx.x;
    const float4* W4 = (const float4*)W1;
    float4* Ws4 = (float4*)Ws;
#pragma unroll
    for (int i = 0; i < 4; i++) Ws4[t + 256 * i] = W4[t + 256 * i];
    int row0 = blockIdx.x * 32;
    const float4* x4 = (const float4*)(x + (size_t)row0 * 128);
    float4* xs4 = (float4*)xs;
#pragma unroll
    for (int i = 0; i < 4; i++) xs4[t + 256 * i] = x4[t + 256 * i];
    __syncthreads();
    int col = t & 31;
    int rb = (t >> 5) * 4;
    float a0 = 0.f, a1 = 0.f, a2 = 0.f, a3 = 0.f;
#pragma unroll 8
    for (int k = 0; k < 128; k++) {
        float w = Ws[k * 32 + col];
        a0 += xs[(rb + 0) * 128 + k] * w;
        a1 += xs[(rb + 1) * 128 + k] * w;
        a2 += xs[(rb + 2) * 128 + k] * w;
        a3 += xs[(rb + 3) * 128 + k] * w;
    }
    int r = row0 + rb;
    __hip_bfloat16* o = H1s + (size_t)r * 32 + col;
    o[0]  = __float2bfloat16(a0 * dinv[r + 0]);
    o[32] = __float2bfloat16(a1 * dinv[r + 1]);
    o[64] = __float2bfloat16(a2 * dinv[r + 2]);
    o[96] = __float2bfloat16(a3 * dinv[r + 3]);
}

// ---------- H2s = bf16( (h1 @ W2) * dinv[row] )  ([100000,32] @ [32,32]) ----------
__global__ void k_gemm2(const float* __restrict__ h1, const float* __restrict__ W2,
                        const float* __restrict__ dinv, __hip_bfloat16* __restrict__ H2s) {
    __shared__ float Ws[32 * 32];
    __shared__ float xs[32 * 32];
    int t = threadIdx.x;
    ((float4*)Ws)[t] = ((const float4*)W2)[t];
    int row0 = blockIdx.x * 32;
    ((float4*)xs)[t] = ((const float4*)(h1 + (size_t)row0 * 32))[t];
    __syncthreads();
    int col = t & 31;
    int rb = (t >> 5) * 4;
    float a0 = 0.f, a1 = 0.f, a2 = 0.f, a3 = 0.f;
#pragma unroll
    for (int k = 0; k < 32; k++) {
        float w = Ws[k * 32 + col];
        a0 += xs[(rb + 0) * 32 + k] * w;
        a1 += xs[(rb + 1) * 32 + k] * w;
        a2 += xs[(rb + 2) * 32 + k] * w;
        a3 += xs[(rb + 3) * 32 + k] * w;
    }
    int r = row0 + rb;
    __hip_bfloat16* o = H2s + (size_t)r * 32 + col;
    o[0]  = __float2bfloat16(a0 * dinv[r + 0]);
    o[32] = __float2bfloat16(a1 * dinv[r + 1]);
    o[64] = __float2bfloat16(a2 * dinv[r + 2]);
    o[96] = __float2bfloat16(a3 * dinv[r + 3]);
}

// ---------- layer-1 aggregation: wave per node, 4 lanes x uint4 per row ----------
// One csr line + 4 row-load instructions put the node's ENTIRE edge list
// (<=64 edges) in flight: 8x the MLP of the 16-lane-x-4B layout.
__global__ void k_gather1(const __hip_bfloat16* __restrict__ Hs, const float* __restrict__ dinv,
                          const int* __restrict__ rp, const int* __restrict__ rpe,
                          const int* __restrict__ csr,
                          const float* __restrict__ bias, float* __restrict__ hout) {
    int wid = (blockIdx.x * 256 + threadIdx.x) >> 6;
    if (wid >= N_NODES) return;
    const uint4* H4 = (const uint4*)Hs;          // row = 4 x uint4 (64B)
    int lane = threadIdx.x & 63;
    int fb = lane & 3;                           // feature quad (uint4) within row
    int es = lane >> 2;                          // edge sub-slot 0..15
    int beg = rp[wid];
    int deg = rpe[wid] - beg;
    float a0=0.f,a1=0.f,a2=0.f,a3=0.f,a4=0.f,a5=0.f,a6=0.f,a7=0.f;
    for (int eb = 0; eb < deg; eb += 64) {       // single iteration for deg<=64 (always here)
        int cv = csr[beg + eb + lane];           // slack slots exist; garbage is predicated off
#pragma unroll
        for (int k = 0; k < 4; k++) {
            int e = eb + es + 16 * k;
            int src = __shfl(cv, es + 16 * k);
            if (e < deg) {
                uint4 v = H4[(size_t)src * 4 + fb];
                a0 += blo(v.x); a1 += bhi(v.x);
                a2 += blo(v.y); a3 += bhi(v.y);
                a4 += blo(v.z); a5 += bhi(v.z);
                a6 += blo(v.w); a7 += bhi(v.w);
            }
        }
    }
#pragma unroll
    for (int m = 4; m <= 32; m <<= 1) {          // reduce lanes sharing fb (bits 2..5)
        a0 += __shfl_xor(a0, m); a1 += __shfl_xor(a1, m);
        a2 += __shfl_xor(a2, m); a3 += __shfl_xor(a3, m);
        a4 += __shfl_xor(a4, m); a5 += __shfl_xor(a5, m);
        a6 += __shfl_xor(a6, m); a7 += __shfl_xor(a7, m);
    }
    if (es == 0) {
        float di = dinv[wid];
        uint4 vw = H4[(size_t)wid * 4 + fb];
        float4 bA = *(const float4*)(bias + fb * 8);
        float4 bB = *(const float4*)(bias + fb * 8 + 4);
        float4 oA, oB;
        oA.x = fmaxf((a0 + blo(vw.x)) * di + bA.x, 0.f);
        oA.y = fmaxf((a1 + bhi(vw.x)) * di + bA.y, 0.f);
        oA.z = fmaxf((a2 + blo(vw.y)) * di + bA.z, 0.f);
        oA.w = fmaxf((a3 + bhi(vw.y)) * di + bA.w, 0.f);
        oB.x = fmaxf((a4 + blo(vw.z)) * di + bB.x, 0.f);
        oB.y = fmaxf((a5 + bhi(vw.z)) * di + bB.y, 0.f);
        oB.z = fmaxf((a6 + blo(vw.w)) * di + bB.z, 0.f);
        oB.w = fmaxf((a7 + bhi(vw.w)) * di + bB.w, 0.f);
        float* o = hout + (size_t)wid * 32 + fb * 8;
        *(float4*)o = oA;
        *(float4*)(o + 4) = oB;
    }
}

// ---------- layer-2 aggregation fused with mean-pool numerator ----------
__global__ void k_gather2(const __hip_bfloat16* __restrict__ Hs, const float* __restrict__ dinv,
                          const int* __restrict__ rp, const int* __restrict__ rpe,
                          const int* __restrict__ csr,
                          const float* __restrict__ bias, const int* __restrict__ batch,
                          float* __restrict__ pool) {
    int wid = (blockIdx.x * 256 + threadIdx.x) >> 6;
    if (wid >= N_NODES) return;
    const uint4* H4 = (const uint4*)Hs;
    int lane = threadIdx.x & 63;
    int fb = lane & 3;
    int es = lane >> 2;
    int beg = rp[wid];
    int deg = rpe[wid] - beg;
    float a0=0.f,a1=0.f,a2=0.f,a3=0.f,a4=0.f,a5=0.f,a6=0.f,a7=0.f;
    for (int eb = 0; eb < deg; eb += 64) {
        int cv = csr[beg + eb + lane];
#pragma unroll
        for (int k = 0; k < 4; k++) {
            int e = eb + es + 16 * k;
            int src = __shfl(cv, es + 16 * k);
            if (e < deg) {
                uint4 v = H4[(size_t)src * 4 + fb];
                a0 += blo(v.x); a1 += bhi(v.x);
                a2 += blo(v.y); a3 += bhi(v.y);
                a4 += blo(v.z); a5 += bhi(v.z);
                a6 += blo(v.w); a7 += bhi(v.w);
            }
        }
    }
#pragma unroll
    for (int m = 4; m <= 32; m <<= 1) {
        a0 += __shfl_xor(a0, m); a1 += __shfl_xor(a1, m);
        a2 += __shfl_xor(a2, m); a3 += __shfl_xor(a3, m);
        a4 += __shfl_xor(a4, m); a5 += __shfl_xor(a5, m);
        a6 += __shfl_xor(a6, m); a7 += __shfl_xor(a7, m);
    }
    if (es == 0) {
        float di = dinv[wid];
        uint4 vw = H4[(size_t)wid * 4 + fb];
        float4 bA = *(const float4*)(bias + fb * 8);
        float4 bB = *(const float4*)(bias + fb * 8 + 4);
        float v0 = fmaxf((a0 + blo(vw.x)) * di + bA.x, 0.f);
        float v1 = fmaxf((a1 + bhi(vw.x)) * di + bA.y, 0.f);
        float v2 = fmaxf((a2 + blo(vw.y)) * di + bA.z, 0.f);
        float v3 = fmaxf((a3 + bhi(vw.y)) * di + bA.w, 0.f);
        float v4 = fmaxf((a4 + blo(vw.z)) * di + bB.x, 0.f);
        float v5 = fmaxf((a5 + bhi(vw.z)) * di + bB.y, 0.f);
        float v6 = fmaxf((a6 + blo(vw.w)) * di + bB.z, 0.f);
        float v7 = fmaxf((a7 + bhi(vw.w)) * di + bB.w, 0.f);
        float* p = pool + (size_t)batch[wid] * 32 + fb * 8;
        atomicAdd(p + 0, v0); atomicAdd(p + 1, v1);
        atomicAdd(p + 2, v2); atomicAdd(p + 3, v3);
        atomicAdd(p + 4, v4); atomicAdd(p + 5, v5);
        atomicAdd(p + 6, v6); atomicAdd(p + 7, v7);
    }
}

// ---------- head ----------
__global__ void k_final(const float* __restrict__ pool, const int* __restrict__ cnt,
                        const float* __restrict__ Wl, const float* __restrict__ bl,
                        float* __restrict__ out) {
    int g = blockIdx.x * 256 + threadIdx.x;
    if (g >= N_GRAPHS) return;
    float inv = 1.0f / fmaxf((float)cnt[g], 1.0f);
    float a0 = bl[0], a1 = bl[1];
#pragma unroll
    for (int f = 0; f < 32; f++) {
        float p = pool[g * 32 + f] * inv;
        a0 += p * Wl[f * 2 + 0];
        a1 += p * Wl[f * 2 + 1];
    }
    out[g * 2 + 0] = a0;
    out[g * 2 + 1] = a1;
}

extern "C" void kernel_launch(void* const* d_in, const int* in_sizes, int n_in,
                              void* d_out, int out_size, void* d_ws, size_t ws_size,
                              hipStream_t stream) {
    const float* x    = (const float*)d_in[0];
    const int*   ei   = (const int*)d_in[1];
    const int*   batch= (const int*)d_in[2];
    const float* W1   = (const float*)d_in[3];
    const float* b1   = (const float*)d_in[4];
    const float* W2   = (const float*)d_in[5];
    const float* b2   = (const float*)d_in[6];
    const float* Wl   = (const float*)d_in[7];
    const float* bl   = (const float*)d_in[8];
    float* out = (float*)d_out;

    char* w = (char*)d_ws;
    size_t off = 0;
    auto take = [&](size_t bytes) -> char* {
        char* p = w + off;
        off = (off + bytes + 255) & ~(size_t)255;
        return p;
    };
    __hip_bfloat16* H1s = (__hip_bfloat16*)take((size_t)N_NODES * 32 * 2);
    float*          h1  = (float*)take((size_t)N_NODES * 32 * 4);
    // packed (16 MB) and H2s (6.4 MB) alias: disjoint lifetimes
    // (packed dies at k_csr; H2s born at k_gemm2).
    char*           shared = take((size_t)NBUK * CAP * 4);
    unsigned*       packed = (unsigned*)shared;
    __hip_bfloat16* H2s    = (__hip_bfloat16*)shared;
    int*      csr    = (int*)  take((size_t)NBUK * CAP * 4);
    float*    dinv   = (float*)take((size_t)N_NODES * 4);
    int*      rp     = (int*)  take((size_t)N_NODES * 4);
    int*      rpe    = (int*)  take((size_t)N_NODES * 4);
    int*      gcnt   = (int*)  take((size_t)NBUK * 4);
    float*    pool   = (float*)take((size_t)N_GRAPHS * 32 * 4);
    int*      cnt    = (int*)  take((size_t)N_GRAPHS * 4);

    hipMemsetAsync(gcnt, 0, (size_t)NBUK * 4, stream);
    hipMemsetAsync(pool, 0, (size_t)N_GRAPHS * 32 * 4, stream);
    hipMemsetAsync(cnt, 0, (size_t)N_GRAPHS * 4, stream);

    k_binfill<<<FILL_BLOCKS, 1024, 0, stream>>>(ei, gcnt, packed);
    k_csr    <<<NBUK, 1024, 0, stream>>>(packed, gcnt, batch, rp, rpe, dinv, csr, cnt);
    k_gemm1  <<<N_NODES / 32, 256, 0, stream>>>(x, W1, dinv, H1s);
    k_gather1<<<N_NODES / 4, 256, 0, stream>>>(H1s, dinv, rp, rpe, csr, b1, h1);
    k_gemm2  <<<N_NODES / 32, 256, 0, stream>>>(h1, W2, dinv, H2s);
    k_gather2<<<N_NODES / 4, 256, 0, stream>>>(H2s, dinv, rp, rpe, csr, b2, batch, pool);
    k_final  <<<2, 256, 0, stream>>>(pool, cnt, Wl, bl, out);
}

// Round 5
// 289.912 us; speedup vs baseline: 5.8104x; 1.7969x over previous
//
#include <hip/hip_runtime.h>
#include <hip/hip_bf16.h>

#define N_NODES 100000
#define N_EDGES 3200000
#define N_GRAPHS 512
#define NBUK 782               // dst buckets of 128 nodes
#define CAP 4608               // slots per bucket (mean 4096, sigma~64, 8-sigma slack)
#define FILL_CHUNK 8192
#define FILL_BLOCKS ((N_EDGES + FILL_CHUNK - 1) / FILL_CHUNK)   // 391

__device__ __forceinline__ float blo(unsigned v) { return __uint_as_float(v << 16); }
__device__ __forceinline__ float bhi(unsigned v) { return __uint_as_float(v & 0xffff0000u); }

// ---------- pass 1: bin edges into fixed bucket slots ----------
// 391 blocks (was 196 -> under CU count). LDS-staged, bucket-grouped writeout.
__global__ __launch_bounds__(1024) void k_binfill(const int* __restrict__ ei,
                                                  int* __restrict__ gcnt,
                                                  unsigned* __restrict__ packed) {
    __shared__ int h[NBUK];
    __shared__ int base[NBUK];
    __shared__ int sb[NBUK];       // block-local exclusive scan of h
    __shared__ int sc[1024];
    __shared__ unsigned buf[FILL_CHUNK] __attribute__((aligned(16)));
    int t = threadIdx.x;
    for (int i = t; i < NBUK; i += 1024) h[i] = 0;
    __syncthreads();
    int s0 = blockIdx.x * FILL_CHUNK;
    int ng = min(FILL_CHUNK, N_EDGES - s0) >> 2;   // 4-entry groups (2048 or 1280)
    const int4* src4 = (const int4*)(ei + s0);
    const int4* dst4 = (const int4*)(ei + N_EDGES + s0);
    int4 sv[2], dv[2];
    int  rk[2][4];
#pragma unroll
    for (int g = 0; g < 2; g++) {
        int gi = t + g * 1024;
        if (gi < ng) {
            sv[g] = src4[gi];
            dv[g] = dst4[gi];
            rk[g][0] = atomicAdd(&h[dv[g].x >> 7], 1);
            rk[g][1] = atomicAdd(&h[dv[g].y >> 7], 1);
            rk[g][2] = atomicAdd(&h[dv[g].z >> 7], 1);
            rk[g][3] = atomicAdd(&h[dv[g].w >> 7], 1);
        }
    }
    __syncthreads();
    for (int i = t; i < NBUK; i += 1024) {
        int c = h[i];
        base[i] = c ? atomicAdd(&gcnt[i], c) : 0;
    }
    sc[t] = (t < NBUK) ? h[t] : 0;
    __syncthreads();
    for (int off = 1; off < 1024; off <<= 1) {
        int x = (t >= off) ? sc[t - off] : 0;
        __syncthreads();
        sc[t] += x;
        __syncthreads();
    }
    for (int i = t; i < NBUK; i += 1024) sb[i] = sc[i] - h[i];
    __syncthreads();
#pragma unroll
    for (int g = 0; g < 2; g++) {
        int gi = t + g * 1024;
        if (gi < ng) {
            int s[4] = {sv[g].x, sv[g].y, sv[g].z, sv[g].w};
            int d[4] = {dv[g].x, dv[g].y, dv[g].z, dv[g].w};
#pragma unroll
            for (int k = 0; k < 4; k++) {
                int bk = d[k] >> 7;
                buf[sb[bk] + rk[g][k]] = (unsigned)s[k] | (((unsigned)d[k] & 127u) << 17);
            }
        }
    }
    __syncthreads();
    int w = t >> 6, lane = t & 63;
    for (int bk = w; bk < NBUK; bk += 16) {
        int c = h[bk];
        if (!c) continue;
        unsigned* gp = packed + (size_t)bk * CAP + base[bk];
        int lb = sb[bk];
        for (int j = lane; j < c; j += 64) gp[j] = buf[lb + j];
    }
}

// ---------- pass 2: per-bucket deg/rp/rpe/dinv + slotted CSR ----------
// 782 blocks x 512 threads (8 waves) -> 4 blocks/CU capacity (was 1.5).
__global__ __launch_bounds__(512) void k_csr(const unsigned* __restrict__ packed,
                                             const int* __restrict__ gcnt,
                                             int* __restrict__ rp, int* __restrict__ rpe,
                                             float* __restrict__ dinv,
                                             int* __restrict__ csr) {
    __shared__ int deg[128];
    __shared__ int sd[128];
    __shared__ int nb0[128];
    __shared__ int lcsr[CAP] __attribute__((aligned(16)));
    int t = threadIdx.x;
    int b = blockIdx.x;
    if (t < 128) deg[t] = 0;
    __syncthreads();
    int n = gcnt[b];
    const unsigned* pb = packed + (size_t)b * CAP;
    unsigned pv[3][4];
    int rk[3][4];
#pragma unroll
    for (int g = 0; g < 3; g++) {
        int i0 = 4 * (t + g * 512);
        if (i0 < n) {
            if (i0 + 3 < n) {
                uint4 p = *(const uint4*)(pb + i0);
                pv[g][0] = p.x; pv[g][1] = p.y; pv[g][2] = p.z; pv[g][3] = p.w;
            } else {
#pragma unroll
                for (int k = 0; k < 4; k++) pv[g][k] = (i0 + k < n) ? pb[i0 + k] : 0u;
            }
#pragma unroll
            for (int k = 0; k < 4; k++)
                if (i0 + k < n) rk[g][k] = atomicAdd(&deg[pv[g][k] >> 17], 1);
        }
    }
    __syncthreads();
    int d = (t < 128) ? deg[t] : 0;
    if (t < 128) sd[t] = d;
    __syncthreads();
    for (int off = 1; off < 128; off <<= 1) {
        int x = (t >= off && t < 128) ? sd[t - off] : 0;
        __syncthreads();
        if (t < 128) sd[t] += x;
        __syncthreads();
    }
    if (t < 128) {
        int l0 = sd[t] - d;           // local base within bucket
        nb0[t] = l0;
        int node = b * 128 + t;
        if (node < N_NODES) {
            rp[node] = b * CAP + l0;
            rpe[node] = b * CAP + l0 + d;
            dinv[node] = rsqrtf((float)d + 1.0f);
        }
    }
    __syncthreads();
#pragma unroll
    for (int g = 0; g < 3; g++) {
        int i0 = 4 * (t + g * 512);
        if (i0 < n) {
#pragma unroll
            for (int k = 0; k < 4; k++) {
                if (i0 + k < n) {
                    unsigned p = pv[g][k];
                    lcsr[nb0[p >> 17] + rk[g][k]] = (int)(p & 0x1FFFFu);
                }
            }
        }
    }
    __syncthreads();
    int n4 = (n + 3) >> 2;
    int4* dst4 = (int4*)(csr + (size_t)b * CAP);
    const int4* sl4 = (const int4*)lcsr;
    for (int i = t; i < n4; i += 512) dst4[i] = sl4[i];
}

// ---------- H1s = bf16( (x @ W1) * dinv[row] )  ([100000,128] @ [128,32]) ----------
__global__ void k_gemm1(const float* __restrict__ x, const float* __restrict__ W1,
                        const float* __restrict__ dinv, __hip_bfloat16* __restrict__ H1s) {
    __shared__ float Ws[128 * 32];
    __shared__ float xs[32 * 128];
    int t = threadIdx.x;
    const float4* W4 = (const float4*)W1;
    float4* Ws4 = (float4*)Ws;
#pragma unroll
    for (int i = 0; i < 4; i++) Ws4[t + 256 * i] = W4[t + 256 * i];
    int row0 = blockIdx.x * 32;
    const float4* x4 = (const float4*)(x + (size_t)row0 * 128);
    float4* xs4 = (float4*)xs;
#pragma unroll
    for (int i = 0; i < 4; i++) xs4[t + 256 * i] = x4[t + 256 * i];
    __syncthreads();
    int col = t & 31;
    int rb = (t >> 5) * 4;
    float a0 = 0.f, a1 = 0.f, a2 = 0.f, a3 = 0.f;
#pragma unroll 8
    for (int k = 0; k < 128; k++) {
        float w = Ws[k * 32 + col];
        a0 += xs[(rb + 0) * 128 + k] * w;
        a1 += xs[(rb + 1) * 128 + k] * w;
        a2 += xs[(rb + 2) * 128 + k] * w;
        a3 += xs[(rb + 3) * 128 + k] * w;
    }
    int r = row0 + rb;
    __hip_bfloat16* o = H1s + (size_t)r * 32 + col;
    o[0]  = __float2bfloat16(a0 * dinv[r + 0]);
    o[32] = __float2bfloat16(a1 * dinv[r + 1]);
    o[64] = __float2bfloat16(a2 * dinv[r + 2]);
    o[96] = __float2bfloat16(a3 * dinv[r + 3]);
}

// ---------- H2s = bf16( (h1 @ W2) * dinv[row] )  ([100000,32] @ [32,32]) ----------
__global__ void k_gemm2(const float* __restrict__ h1, const float* __restrict__ W2,
                        const float* __restrict__ dinv, __hip_bfloat16* __restrict__ H2s) {
    __shared__ float Ws[32 * 32];
    __shared__ float xs[32 * 32];
    int t = threadIdx.x;
    ((float4*)Ws)[t] = ((const float4*)W2)[t];
    int row0 = blockIdx.x * 32;
    ((float4*)xs)[t] = ((const float4*)(h1 + (size_t)row0 * 32))[t];
    __syncthreads();
    int col = t & 31;
    int rb = (t >> 5) * 4;
    float a0 = 0.f, a1 = 0.f, a2 = 0.f, a3 = 0.f;
#pragma unroll
    for (int k = 0; k < 32; k++) {
        float w = Ws[k * 32 + col];
        a0 += xs[(rb + 0) * 32 + k] * w;
        a1 += xs[(rb + 1) * 32 + k] * w;
        a2 += xs[(rb + 2) * 32 + k] * w;
        a3 += xs[(rb + 3) * 32 + k] * w;
    }
    int r = row0 + rb;
    __hip_bfloat16* o = H2s + (size_t)r * 32 + col;
    o[0]  = __float2bfloat16(a0 * dinv[r + 0]);
    o[32] = __float2bfloat16(a1 * dinv[r + 1]);
    o[64] = __float2bfloat16(a2 * dinv[r + 2]);
    o[96] = __float2bfloat16(a3 * dinv[r + 3]);
}

// ---------- aggregation: wave per node, 4 lanes x uint4 per row, 64 edges in flight ----
// Used for BOTH layers: reads bf16 H rows, writes f32 relu'd rows (coalesced,
// NO atomics -- round-4's sparse-lane atomic epilogue was a 4x sector-write amp).
__global__ void k_gather(const __hip_bfloat16* __restrict__ Hs, const float* __restrict__ dinv,
                         const int* __restrict__ rp, const int* __restrict__ rpe,
                         const int* __restrict__ csr,
                         const float* __restrict__ bias, float* __restrict__ hout) {
    int wid = (blockIdx.x * 256 + threadIdx.x) >> 6;
    if (wid >= N_NODES) return;
    const uint4* H4 = (const uint4*)Hs;          // row = 4 x uint4 (64B)
    int lane = threadIdx.x & 63;
    int fb = lane & 3;                           // feature quad (uint4) within row
    int es = lane >> 2;                          // edge sub-slot 0..15
    int beg = rp[wid];
    int deg = rpe[wid] - beg;
    float a0=0.f,a1=0.f,a2=0.f,a3=0.f,a4=0.f,a5=0.f,a6=0.f,a7=0.f;
    for (int eb = 0; eb < deg; eb += 64) {       // single iteration for deg<=64
        int cv = csr[beg + eb + lane];           // slack slots; garbage predicated off
#pragma unroll
        for (int k = 0; k < 4; k++) {
            int e = eb + es + 16 * k;
            int src = __shfl(cv, es + 16 * k);
            if (e < deg) {
                uint4 v = H4[(size_t)src * 4 + fb];
                a0 += blo(v.x); a1 += bhi(v.x);
                a2 += blo(v.y); a3 += bhi(v.y);
                a4 += blo(v.z); a5 += bhi(v.z);
                a6 += blo(v.w); a7 += bhi(v.w);
            }
        }
    }
#pragma unroll
    for (int m = 4; m <= 32; m <<= 1) {          // reduce lanes sharing fb
        a0 += __shfl_xor(a0, m); a1 += __shfl_xor(a1, m);
        a2 += __shfl_xor(a2, m); a3 += __shfl_xor(a3, m);
        a4 += __shfl_xor(a4, m); a5 += __shfl_xor(a5, m);
        a6 += __shfl_xor(a6, m); a7 += __shfl_xor(a7, m);
    }
    if (es == 0) {
        float di = dinv[wid];
        uint4 vw = H4[(size_t)wid * 4 + fb];
        float4 bA = *(const float4*)(bias + fb * 8);
        float4 bB = *(const float4*)(bias + fb * 8 + 4);
        float4 oA, oB;
        oA.x = fmaxf((a0 + blo(vw.x)) * di + bA.x, 0.f);
        oA.y = fmaxf((a1 + bhi(vw.x)) * di + bA.y, 0.f);
        oA.z = fmaxf((a2 + blo(vw.y)) * di + bA.z, 0.f);
        oA.w = fmaxf((a3 + bhi(vw.y)) * di + bA.w, 0.f);
        oB.x = fmaxf((a4 + blo(vw.z)) * di + bB.x, 0.f);
        oB.y = fmaxf((a5 + bhi(vw.z)) * di + bB.y, 0.f);
        oB.z = fmaxf((a6 + blo(vw.w)) * di + bB.z, 0.f);
        oB.w = fmaxf((a7 + bhi(vw.w)) * di + bB.w, 0.f);
        float* o = hout + (size_t)wid * 32 + fb * 8;
        *(float4*)o = oA;
        *(float4*)(o + 4) = oB;
    }
}

// ---------- per-graph mean pool + head (no atomics; batch is sorted) ----------
__global__ __launch_bounds__(256) void k_pool(const float* __restrict__ h2,
                                              const int* __restrict__ batch,
                                              const float* __restrict__ Wl,
                                              const float* __restrict__ bl,
                                              float* __restrict__ out) {
    __shared__ float red[256];
    __shared__ float pooled[32];
    int g = blockIdx.x;
    int t = threadIdx.x;
    int lo = 0, hi = N_NODES;
    while (lo < hi) { int m = (lo + hi) >> 1; if (batch[m] < g) lo = m + 1; else hi = m; }
    int s = lo;
    hi = N_NODES;
    while (lo < hi) { int m = (lo + hi) >> 1; if (batch[m] < g + 1) lo = m + 1; else hi = m; }
    int e = lo;
    int f = t & 31, r0 = t >> 5;
    float acc = 0.f;
    for (int r = s + r0; r < e; r += 8) acc += h2[(size_t)r * 32 + f];
    red[t] = acc;
    __syncthreads();
    for (int off = 128; off >= 32; off >>= 1) {
        if (t < off) red[t] += red[t + off];
        __syncthreads();
    }
    if (t < 32) pooled[t] = red[t] / fmaxf((float)(e - s), 1.0f);
    __syncthreads();
    if (t < 2) {
        float a = bl[t];
#pragma unroll
        for (int k = 0; k < 32; k++) a += pooled[k] * Wl[k * 2 + t];
        out[g * 2 + t] = a;
    }
}

extern "C" void kernel_launch(void* const* d_in, const int* in_sizes, int n_in,
                              void* d_out, int out_size, void* d_ws, size_t ws_size,
                              hipStream_t stream) {
    const float* x    = (const float*)d_in[0];
    const int*   ei   = (const int*)d_in[1];
    const int*   batch= (const int*)d_in[2];
    const float* W1   = (const float*)d_in[3];
    const float* b1   = (const float*)d_in[4];
    const float* W2   = (const float*)d_in[5];
    const float* b2   = (const float*)d_in[6];
    const float* Wl   = (const float*)d_in[7];
    const float* bl   = (const float*)d_in[8];
    float* out = (float*)d_out;

    char* w = (char*)d_ws;
    size_t off = 0;
    auto take = [&](size_t bytes) -> char* {
        char* p = w + off;
        off = (off + bytes + 255) & ~(size_t)255;
        return p;
    };
    __hip_bfloat16* H1s = (__hip_bfloat16*)take((size_t)N_NODES * 32 * 2);   //  6.4 MB
    float*          h1  = (float*)take((size_t)N_NODES * 32 * 4);            // 12.8 MB (also h2 out)
    // packed (14.4 MB) and H2s (6.4 MB) alias: disjoint lifetimes
    // (packed dies at k_csr; H2s born at k_gemm2).
    char*           shared = take((size_t)NBUK * CAP * 4);
    unsigned*       packed = (unsigned*)shared;
    __hip_bfloat16* H2s    = (__hip_bfloat16*)shared;
    int*      csr    = (int*)  take((size_t)NBUK * CAP * 4 + 1024);          // +pad for 63-slot overread
    float*    dinv   = (float*)take((size_t)N_NODES * 4);
    int*      rp     = (int*)  take((size_t)N_NODES * 4);
    int*      rpe    = (int*)  take((size_t)N_NODES * 4);
    int*      gcnt   = (int*)  take((size_t)NBUK * 4);

    hipMemsetAsync(gcnt, 0, (size_t)NBUK * 4, stream);

    k_binfill<<<FILL_BLOCKS, 1024, 0, stream>>>(ei, gcnt, packed);
    k_csr    <<<NBUK, 512, 0, stream>>>(packed, gcnt, rp, rpe, dinv, csr);
    k_gemm1  <<<N_NODES / 32, 256, 0, stream>>>(x, W1, dinv, H1s);
    k_gather <<<N_NODES / 4, 256, 0, stream>>>(H1s, dinv, rp, rpe, csr, b1, h1);
    k_gemm2  <<<N_NODES / 32, 256, 0, stream>>>(h1, W2, dinv, H2s);
    k_gather <<<N_NODES / 4, 256, 0, stream>>>(H2s, dinv, rp, rpe, csr, b2, h1);
    k_pool   <<<N_GRAPHS, 256, 0, stream>>>(h1, batch, Wl, bl, out);
}